// Round 8
// baseline (247.200 us; speedup 1.0000x reference)
//
#include <hip/hip_runtime.h>

#define NCACHE 384

__device__ __forceinline__ unsigned int sortable_bits(float f) {
    unsigned int u = __float_as_uint(f);
    return (u & 0x80000000u) ? ~u : (u | 0x80000000u);
}

// 256 threads = 4 waves; wave w handles b = blockIdx.x*4 + w entirely.
__global__ __launch_bounds__(256) void fused_kernel(
    const float*  __restrict__ cache,        // (384,5)
    const float*  __restrict__ refdirs,      // (B,3)
    const float*  __restrict__ normal,       // (B,3)
    const float4* __restrict__ samp_rays4,   // B*96 float4
    const float4* __restrict__ samp_mip4,    // B*32 float4
    float* __restrict__ out, int B)
{
#pragma clang fp contract(off)
    __shared__ float sdx[NCACHE], sdy[NCACHE], sdz[NCACHE], smip[NCACHE];
    __shared__ unsigned int bitmap[4][12];

    const int tid  = threadIdx.x;
    const int wave = tid >> 6;
    const int lane = tid & 63;
    const int b    = blockIdx.x * 4 + wave;

    // Early-issue pass-through copy loads (hide HBM under the rank loop).
    const int b0 = blockIdx.x * 4;
    const int i0 = tid, i1 = tid + 256;
    const int bb0 = b0 + (i0 >> 7), off0 = i0 & 127;
    const int bb1 = b0 + (i1 >> 7), off1 = i1 & 127;
    const float4 c0 = (off0 < 96) ? samp_rays4[(size_t)bb0 * 96 + off0]
                                  : samp_mip4[(size_t)bb0 * 32 + (off0 - 96)];
    const float4 c1 = (off1 < 96) ? samp_rays4[(size_t)bb1 * 96 + off1]
                                  : samp_mip4[(size_t)bb1 * 32 + (off1 - 96)];

    // Stage cache into LDS (cooperative, once per block)
    for (int m = tid; m < NCACHE; m += 256) {
        sdx[m]  = cache[m * 5 + 0];
        sdy[m]  = cache[m * 5 + 1];
        sdz[m]  = cache[m * 5 + 2];
        smip[m] = cache[m * 5 + 3];
    }
    if (tid < 48) (&bitmap[0][0])[tid] = 0u;

    const float nx = normal[b * 3 + 0], ny = normal[b * 3 + 1], nz = normal[b * 3 + 2];
    const float rx = refdirs[b * 3 + 0], ry = refdirs[b * 3 + 1], rz = refdirs[b * 3 + 2];

    __syncthreads();

    // Scores -> sortable value words, kept in REGISTERS (no LDS round-trip).
    // FMA left-chains, bit-exact vs reference; -0.0 canonicalized to +0.0.
    // Full key for index j is (svhi << 32) | j; the low word is a constant.
    unsigned int svhi[6];
#pragma unroll
    for (int c = 0; c < 6; ++c) {
        const int m = c * 64 + lane;
        float dx = sdx[m], dy = sdy[m], dz = sdz[m];
        float hemi = __builtin_fmaf(nz, dz, __builtin_fmaf(ny, dy, nx * dx));
        float sim  = __builtin_fmaf(rz, dz, __builtin_fmaf(ry, dy, rx * dx));
        float val  = (hemi > 0.0f) ? -sim : 0.0f;
        val = val + 0.0f;
        svhi[c] = sortable_bits(val);
    }
    const unsigned long long key0 =
        ((unsigned long long)svhi[0] << 32) | (unsigned int)lane;
    const unsigned long long key1 =
        ((unsigned long long)svhi[1] << 32) | (unsigned int)(lane + 64);

    // Transposed rank loop, LDS-free: broadcast key_j's value word via
    // v_readlane (1 VALU) -> SGPR; low word is the constant j. 64-bit compare
    // takes the SGPR pair as src0: 5 VALU per j serving 128 pairs.
    unsigned int r0 = 0, r1 = 0;
#pragma unroll
    for (int c2 = 0; c2 < 6; ++c2) {
#pragma unroll
        for (int l = 0; l < 64; ++l) {
            const unsigned int jh =
                (unsigned int)__builtin_amdgcn_readlane((int)svhi[c2], l);
            const unsigned long long kj =
                ((unsigned long long)jh << 32) | (unsigned int)(c2 * 64 + l);
            asm("v_cmp_lt_u64 vcc, %[kj], %[k0]\n\t"
                "v_addc_co_u32 %[r0], vcc, 0, %[r0], vcc\n\t"
                "v_cmp_lt_u64 vcc, %[kj], %[k1]\n\t"
                "v_addc_co_u32 %[r1], vcc, 0, %[r1], vcc"
                : [r0] "+v"(r0), [r1] "+v"(r1)
                : [kj] "s"(kj), [k0] "v"(key0), [k1] "v"(key1)
                : "vcc");
        }
    }

    // Ranks are distinct in [0,384). Output slot = #{selected ranks < r}.
    // bitmap[wave] is touched only by this wave; DS ops of one wave complete
    // in order, so no block barrier is needed.
    atomicOr(&bitmap[wave][r0 >> 5], 1u << (r0 & 31));
    atomicOr(&bitmap[wave][r1 >> 5], 1u << (r1 & 31));

    float* out_rays = out;
    float* out_mip  = out + (size_t)B * 768;

    {
        const int wi = (int)r0 >> 5;
        int s = __popc(bitmap[wave][wi] & ((1u << (r0 & 31)) - 1u));
        for (int w = 0; w < wi; ++w) s += __popc(bitmap[wave][w]);
        const size_t rb = (size_t)b * 768 + 384 + (size_t)s * 3;
        out_rays[rb + 0] = sdx[r0];
        out_rays[rb + 1] = sdy[r0];
        out_rays[rb + 2] = sdz[r0];
        out_mip[(size_t)b * 256 + 128 + s] = smip[r0];
    }
    {
        const int wi = (int)r1 >> 5;
        int s = __popc(bitmap[wave][wi] & ((1u << (r1 & 31)) - 1u));
        for (int w = 0; w < wi; ++w) s += __popc(bitmap[wave][w]);
        const size_t rb = (size_t)b * 768 + 384 + (size_t)s * 3;
        out_rays[rb + 0] = sdx[r1];
        out_rays[rb + 1] = sdy[r1];
        out_rays[rb + 2] = sdz[r1];
        out_mip[(size_t)b * 256 + 128 + s] = smip[r1];
    }

    // Pass-through copy stores (loads issued at kernel entry).
    float4* out4     = (float4*)out;
    float4* out_mip4 = (float4*)(out + (size_t)B * 768);
    if (off0 < 96) out4[(size_t)bb0 * 192 + off0] = c0;
    else           out_mip4[(size_t)bb0 * 64 + (off0 - 96)] = c0;
    if (off1 < 96) out4[(size_t)bb1 * 192 + off1] = c1;
    else           out_mip4[(size_t)bb1 * 64 + (off1 - 96)] = c1;
}

extern "C" void kernel_launch(void* const* d_in, const int* in_sizes, int n_in,
                              void* d_out, int out_size, void* d_ws, size_t ws_size,
                              hipStream_t stream) {
    const float* cache       = (const float*)d_in[0];
    const float* refdirs     = (const float*)d_in[1];
    const float* normal      = (const float*)d_in[2];
    const float* samp_rays   = (const float*)d_in[3];
    const float* samp_mipval = (const float*)d_in[4];
    float* out = (float*)d_out;

    const int B = in_sizes[1] / 3;  // 65536

    fused_kernel<<<B / 4, 256, 0, stream>>>(cache, refdirs, normal,
                                            (const float4*)samp_rays,
                                            (const float4*)samp_mipval,
                                            out, B);
}